// Round 1
// baseline (147.659 us; speedup 1.0000x reference)
//
#include <hip/hip_runtime.h>
#include <math.h>

// StripePolynomial2d: out[b,c,px,py] = (1/8) * sum_i P_i(xs_i), where
//   xs_i = 0.5*x[b,c,px,py] + Ax[i]*px + Ay[i]*py + C0[i]   (folded position map)
//   s    = clamp(floor(xs), 0, 511); t = 2*(xs-s)-1
//   P_i  = w1 + t*(0.5*(w2-w0) + t*(0.5*(w0+w2) - w1)),  w{0,1,2} = weights[i,c,2s..2s+2]
// Weights are staged per-block into an expanded float4 LDS LUT so each gather
// is a single 16B-aligned ds_read_b128.

#define WDIM 512
#define HDIM 512
#define SEGS 512
#define NPOS 8
#define NW   1025
#define CCH  3

#define THREADS 256
#define PIX_PER_THREAD 32
#define PIX_PER_BLOCK (THREADS * PIX_PER_THREAD)   // 8192
#define CHUNKS ((WDIM * HDIM) / PIX_PER_BLOCK)     // 32

struct Params {
    float ax[NPOS];
    float ay[NPOS];
    float c0[NPOS];
};

__global__ __launch_bounds__(THREADS)
void stripe_poly_kernel(const float* __restrict__ x,
                        const float* __restrict__ w,
                        float* __restrict__ out,
                        Params P)
{
    // 8 positions x 512 segments x float4 = 64 KB (2 blocks/CU on 160 KB LDS)
    __shared__ float4 lut[NPOS][SEGS];

    const int slice = blockIdx.x / CHUNKS;   // b*3 + c
    const int chunk = blockIdx.x % CHUNKS;
    const int ch    = slice % CCH;

    // Stage expanded LUT: lut[p][s] = (w[2s], w[2s+1], w[2s+2], 0).
    // 4096 float4s / 256 threads = 16 each; global reads are L1/L2-cached.
    for (int idx = threadIdx.x; idx < NPOS * SEGS; idx += THREADS) {
        const int p = idx >> 9;            // / SEGS
        const int s = idx & (SEGS - 1);
        const float* wp = w + ((size_t)p * CCH + ch) * NW + 2 * s;
        lut[p][s] = make_float4(wp[0], wp[1], wp[2], 0.0f);
    }
    __syncthreads();

    const size_t slice_off = (size_t)slice * (WDIM * HDIM);
    const int base = chunk * PIX_PER_BLOCK;

    for (int k = 0; k < PIX_PER_THREAD / 4; ++k) {
        const int p0 = base + ((k * THREADS + threadIdx.x) << 2); // 4 consecutive pixels (same row)
        const float4 xin = *(const float4*)(x + slice_off + p0);
        const float xf = (float)(p0 >> 9);          // px = p0 / HDIM
        const float yf = (float)(p0 & (HDIM - 1));  // py
        const float xv[4] = {xin.x, xin.y, xin.z, xin.w};
        float acc[4] = {0.f, 0.f, 0.f, 0.f};

        #pragma unroll
        for (int i = 0; i < NPOS; ++i) {
            const float ay = P.ay[i];
            const float g  = fmaf(ay, yf, fmaf(P.ax[i], xf, P.c0[i]));
            #pragma unroll
            for (int j = 0; j < 4; ++j) {
                const float xs = fmaf(0.5f, xv[j], fmaf(ay, (float)j, g));
                float sf = floorf(xs);
                sf = fminf(fmaxf(sf, 0.0f), (float)(SEGS - 1));
                const int s = (int)sf;
                const float t = fmaf(2.0f, xs - sf, -1.0f);
                const float4 wv = lut[i][s];                 // single ds_read_b128
                const float c1 = 0.5f * (wv.z - wv.x);
                const float c2 = fmaf(0.5f, wv.x + wv.z, -wv.y);
                acc[j] += fmaf(t, fmaf(t, c2, c1), wv.y);
            }
        }

        float4 o;
        o.x = acc[0] * 0.125f;
        o.y = acc[1] * 0.125f;
        o.z = acc[2] * 0.125f;
        o.w = acc[3] * 0.125f;
        *(float4*)(out + slice_off + p0) = o;
    }
}

extern "C" void kernel_launch(void* const* d_in, const int* in_sizes, int n_in,
                              void* d_out, int out_size, void* d_ws, size_t ws_size,
                              hipStream_t stream)
{
    const float* x = (const float*)d_in[0];   // [16,3,512,512] f32
    const float* w = (const float*)d_in[1];   // [8,3,1025] f32
    float* out = (float*)d_out;

    // Host-side fold of make_positions() + position_encode + xs rescale.
    // r(x,y) = f32(cx)*x + f32(sgn*cy)*y ; extremes at grid corners (monotone).
    // xs = 0.5*xval + K*(r - rmin), K = 512*RATIO/dr  =>  Ax=K*a, Ay=K*b, C0=-K*rmin.
    Params P;
    const double ratio_f = (double)(float)(512.0 / 513.0);  // numpy casts RATIO to f32
    for (int i = 0; i < 4; ++i) {
        const double theta = (M_PI * 0.5) * ((double)i / 4.0);
        const float a   = (float)cos(theta);
        const float cyf = (float)sin(theta);
        for (int sg = 0; sg < 2; ++sg) {
            const float b = (sg == 0) ? cyf : -cyf;   // f32(sgn*cy)
            // f32 per-op corner values (mul rounded, then add rounded) as numpy does
            const float ax511 = a * 511.0f;
            const float by511 = b * 511.0f;
            float rmin, rmax;
            if (sg == 0) { rmin = 0.0f;  rmax = ax511 + by511; }
            else         { rmin = by511; rmax = ax511; }
            const float dr = rmax - rmin;
            const double K = 512.0 * ratio_f / (double)dr;
            const int pi = 2 * i + sg;
            P.ax[pi] = (float)(K * (double)a);
            P.ay[pi] = (float)(K * (double)b);
            P.c0[pi] = (float)(-K * (double)rmin);
        }
    }

    const int slices = in_sizes[0] / (WDIM * HDIM);  // B*C = 48
    const int blocks = slices * CHUNKS;              // 1536
    stripe_poly_kernel<<<blocks, THREADS, 0, stream>>>(x, w, out, P);
}

// Round 2
// 134.205 us; speedup vs baseline: 1.1003x; 1.1003x over previous
//
#include <hip/hip_runtime.h>
#include <math.h>

// StripePolynomial2d: out[b,c,px,py] = (1/8) * sum_i P_i(xs_i), where
//   xs_i = 0.5*x[b,c,px,py] + Ax[i]*px + Ay[i]*py + C0[i]   (folded position map)
//   s    = clamp(floor(xs), 0, 511); t = 2*(xs-s)-1
//   P_i  = c0 + t*(c1 + t*c2)  with per-segment Horner coeffs precomputed at
//   staging: c0=w1, c1=(w2-w0)/2, c2=(w0+w2)/2-w1.
// LUT entry packed as {f32 c0, f16 c1, f16 c2} = 8 B -> one ds_read_b64 per
// gather, 32 KB LDS total -> 5 blocks/CU (~62% occupancy).

#define WDIM 512
#define HDIM 512
#define SEGS 512
#define NPOS 8
#define NW   1025
#define CCH  3

#define THREADS 256
#define PIX_PER_THREAD 16
#define PIX_PER_BLOCK (THREADS * PIX_PER_THREAD)   // 4096
#define CHUNKS ((WDIM * HDIM) / PIX_PER_BLOCK)     // 64

struct Params {
    float ax[NPOS];
    float ay[NPOS];
    float c0[NPOS];
};

union HalfPack {
    unsigned int u;
    _Float16 h[2];
};

__global__ __launch_bounds__(THREADS, 5)
void stripe_poly_kernel(const float* __restrict__ x,
                        const float* __restrict__ w,
                        float* __restrict__ out,
                        Params P)
{
    // 8 positions x 512 segments x 8 B = 32 KB
    __shared__ uint2 lut[NPOS][SEGS];

    const int slice = blockIdx.x / CHUNKS;   // b*3 + c
    const int chunk = blockIdx.x % CHUNKS;
    const int ch    = slice % CCH;

    // Stage coefficient LUT: 4096 entries / 256 threads = 16 each.
    for (int idx = threadIdx.x; idx < NPOS * SEGS; idx += THREADS) {
        const int p = idx >> 9;            // / SEGS
        const int s = idx & (SEGS - 1);
        const float* wp = w + ((size_t)p * CCH + ch) * NW + 2 * s;
        const float w0 = wp[0], w1 = wp[1], w2 = wp[2];
        const float c1 = 0.5f * (w2 - w0);
        const float c2 = fmaf(0.5f, w0 + w2, -w1);
        HalfPack hp;
        hp.h[0] = (_Float16)c1;
        hp.h[1] = (_Float16)c2;
        lut[p][s] = make_uint2(__float_as_uint(w1), hp.u);
    }
    __syncthreads();

    const size_t slice_off = (size_t)slice * (WDIM * HDIM);
    const int base = chunk * PIX_PER_BLOCK;

    for (int k = 0; k < PIX_PER_THREAD / 4; ++k) {
        const int p0 = base + ((k * THREADS + threadIdx.x) << 2); // 4 consecutive pixels (same row)
        const float4 xin = *(const float4*)(x + slice_off + p0);
        const float xf = (float)(p0 >> 9);          // px
        const float yf = (float)(p0 & (HDIM - 1));  // py
        const float xv[4] = {xin.x, xin.y, xin.z, xin.w};
        float acc[4] = {0.f, 0.f, 0.f, 0.f};

        #pragma unroll
        for (int i = 0; i < NPOS; ++i) {
            const float ay = P.ay[i];
            const float g  = fmaf(ay, yf, fmaf(P.ax[i], xf, P.c0[i]));
            #pragma unroll
            for (int j = 0; j < 4; ++j) {
                const float xs = fmaf(0.5f, xv[j], fmaf(ay, (float)j, g));
                float sf = floorf(xs);
                sf = fminf(fmaxf(sf, 0.0f), (float)(SEGS - 1));
                const int s = (int)sf;
                const float t = fmaf(2.0f, xs - sf, -1.0f);
                const uint2 v = lut[i][s];                 // single ds_read_b64
                HalfPack hp; hp.u = v.y;
                const float c0 = __uint_as_float(v.x);
                const float c1 = (float)hp.h[0];
                const float c2 = (float)hp.h[1];
                acc[j] += c0 + t * fmaf(t, c2, c1);
            }
        }

        float4 o;
        o.x = acc[0] * 0.125f;
        o.y = acc[1] * 0.125f;
        o.z = acc[2] * 0.125f;
        o.w = acc[3] * 0.125f;
        *(float4*)(out + slice_off + p0) = o;
    }
}

extern "C" void kernel_launch(void* const* d_in, const int* in_sizes, int n_in,
                              void* d_out, int out_size, void* d_ws, size_t ws_size,
                              hipStream_t stream)
{
    const float* x = (const float*)d_in[0];   // [16,3,512,512] f32
    const float* w = (const float*)d_in[1];   // [8,3,1025] f32
    float* out = (float*)d_out;

    // Host-side fold of make_positions() + position_encode + xs rescale.
    // r(x,y) = f32(cx)*x + f32(sgn*cy)*y ; extremes at grid corners (monotone).
    // xs = 0.5*xval + K*(r - rmin), K = 512*RATIO/dr  =>  Ax=K*a, Ay=K*b, C0=-K*rmin.
    Params P;
    const double ratio_f = (double)(float)(512.0 / 513.0);  // numpy casts RATIO to f32
    for (int i = 0; i < 4; ++i) {
        const double theta = (M_PI * 0.5) * ((double)i / 4.0);
        const float a   = (float)cos(theta);
        const float cyf = (float)sin(theta);
        for (int sg = 0; sg < 2; ++sg) {
            const float b = (sg == 0) ? cyf : -cyf;   // f32(sgn*cy)
            // f32 per-op corner values (mul rounded, then add rounded) as numpy does
            const float ax511 = a * 511.0f;
            const float by511 = b * 511.0f;
            float rmin, rmax;
            if (sg == 0) { rmin = 0.0f;  rmax = ax511 + by511; }
            else         { rmin = by511; rmax = ax511; }
            const float dr = rmax - rmin;
            const double K = 512.0 * ratio_f / (double)dr;
            const int pi = 2 * i + sg;
            P.ax[pi] = (float)(K * (double)a);
            P.ay[pi] = (float)(K * (double)b);
            P.c0[pi] = (float)(-K * (double)rmin);
        }
    }

    const int slices = in_sizes[0] / (WDIM * HDIM);  // B*C = 48
    const int blocks = slices * CHUNKS;              // 3072
    stripe_poly_kernel<<<blocks, THREADS, 0, stream>>>(x, w, out, P);
}

// Round 3
// 117.310 us; speedup vs baseline: 1.2587x; 1.1440x over previous
//
#include <hip/hip_runtime.h>
#include <math.h>

// StripePolynomial2d: out[b,c,px,py] = sum_i lut_i(xs_i), where
//   xs_i = 0.5*x + Ax[i]*px + Ay[i]*py + C0[i]   (folded position map)
//   s = clamp(floor(xs),0,511); t = 2*(xs-s)-1; P = c0 + t*(c1 + t*c2)
// with the 1/8 normalization folded into the staged coefficients and
// positions 0,1 merged (theta=0 => identical maps => sum their weights).
//
// LDS gather conflicts are controlled by lane mapping: each wave covers a
// 16px x 16py patch. Since K*(a+|b|) ~= 512*RATIO/511 ~= 1.0 for every
// direction, per-gather segment spread is ~16 for all positions ->
// near-conflict-free ds_read_b64.

#define WDIM 512
#define HDIM 512
#define SEGS 512
#define NPOS 8
#define NTAB 7     // position 0+1 merged
#define NW   1025
#define CCH  3

#define THREADS 512
#define TILE 64                       // block covers 64px x 64py
#define TILES_PER_SLICE ((WDIM / TILE) * (HDIM / TILE))  // 64

struct Params {
    float ax[NPOS];
    float ay[NPOS];
    float c0[NPOS];
};

union HalfPack {
    unsigned int u;
    _Float16 h[2];
};

__global__ __launch_bounds__(THREADS, 8)
void stripe_poly_kernel(const float* __restrict__ x,
                        const float* __restrict__ w,
                        float* __restrict__ out,
                        Params P)
{
    // 7 tables x 512 segments x 8 B = 28 KB
    __shared__ uint2 lut[NTAB][SEGS];

    const int slice = blockIdx.x / TILES_PER_SLICE;   // b*3 + c
    const int tile  = blockIdx.x % TILES_PER_SLICE;
    const int ch    = slice % CCH;
    const int bx    = (tile >> 3) * TILE;   // px tile origin
    const int by    = (tile & 7) * TILE;    // py tile origin

    // Stage coefficient LUT (with 1/8 folded in): 3584 entries / 512 thr = 7 ea.
    for (int idx = threadIdx.x; idx < NTAB * SEGS; idx += THREADS) {
        const int m = idx >> 9;            // merged table id
        const int s = idx & (SEGS - 1);
        float w0, w1, w2;
        if (m == 0) {
            const float* wa = w + (size_t)(0 * CCH + ch) * NW + 2 * s;
            const float* wb = w + (size_t)(1 * CCH + ch) * NW + 2 * s;
            w0 = wa[0] + wb[0]; w1 = wa[1] + wb[1]; w2 = wa[2] + wb[2];
        } else {
            const float* wp = w + (size_t)((m + 1) * CCH + ch) * NW + 2 * s;
            w0 = wp[0]; w1 = wp[1]; w2 = wp[2];
        }
        const float c0 = 0.125f * w1;
        const float c1 = 0.0625f * (w2 - w0);
        const float c2 = 0.125f * fmaf(0.5f, w0 + w2, -w1);
        HalfPack hp;
        hp.h[0] = (_Float16)c1;
        hp.h[1] = (_Float16)c2;
        lut[m][s] = make_uint2(__float_as_uint(c0), hp.u);
    }
    __syncthreads();

    // Lane -> patch mapping: wave covers 16px x 16py.
    const int tid  = threadIdx.x;
    const int wv   = tid >> 6;
    const int lane = tid & 63;
    const int px_w = (wv >> 2) * 16;        // 2 px groups of waves
    const int py_w = (wv & 3) * 16;         // 4 py groups of waves
    const int px_l = lane >> 2;             // 0..15
    const int py_l = (lane & 3) * 4;        // 0,4,8,12

    const size_t slice_off = (size_t)slice * (WDIM * HDIM);
    const int py = by + py_w + py_l;
    const float yf = (float)py;

    for (int k = 0; k < 2; ++k) {           // px step 32 between iterations
        const int px = bx + px_w + k * 32 + px_l;
        const size_t p0 = slice_off + (size_t)px * HDIM + py;
        const float4 xin = *(const float4*)(x + p0);
        const float xf = (float)px;
        const float xv[4] = {xin.x, xin.y, xin.z, xin.w};
        float acc[4] = {0.f, 0.f, 0.f, 0.f};

        #pragma unroll
        for (int i = 0; i < NTAB; ++i) {
            const int pi = (i == 0) ? 0 : (i + 1);  // source position index
            const float ay = P.ay[pi];
            const float g  = fmaf(ay, yf, fmaf(P.ax[pi], xf, P.c0[pi]));
            #pragma unroll
            for (int j = 0; j < 4; ++j) {
                const float xs = fmaf(0.5f, xv[j], fmaf(ay, (float)j, g));
                float sf = floorf(xs);
                sf = fminf(fmaxf(sf, 0.0f), (float)(SEGS - 1));
                const int s = (int)sf;
                const float t = fmaf(2.0f, xs - sf, -1.0f);
                const uint2 v = lut[i][s];                 // ds_read_b64
                HalfPack hp; hp.u = v.y;
                const float u = fmaf(t, (float)hp.h[1], (float)hp.h[0]); // fma_mix
                acc[j] = fmaf(t, u, acc[j] + __uint_as_float(v.x));
            }
        }

        float4 o;
        o.x = acc[0]; o.y = acc[1]; o.z = acc[2]; o.w = acc[3];
        *(float4*)(out + p0) = o;
    }
}

extern "C" void kernel_launch(void* const* d_in, const int* in_sizes, int n_in,
                              void* d_out, int out_size, void* d_ws, size_t ws_size,
                              hipStream_t stream)
{
    const float* x = (const float*)d_in[0];   // [16,3,512,512] f32
    const float* w = (const float*)d_in[1];   // [8,3,1025] f32
    float* out = (float*)d_out;

    // Host-side fold of make_positions() + position_encode + xs rescale.
    // r(x,y) = f32(cx)*x + f32(sgn*cy)*y ; extremes at grid corners (monotone).
    // xs = 0.5*xval + K*(r - rmin), K = 512*RATIO/dr  =>  Ax=K*a, Ay=K*b, C0=-K*rmin.
    Params P;
    const double ratio_f = (double)(float)(512.0 / 513.0);  // numpy casts RATIO to f32
    for (int i = 0; i < 4; ++i) {
        const double theta = (M_PI * 0.5) * ((double)i / 4.0);
        const float a   = (float)cos(theta);
        const float cyf = (float)sin(theta);
        for (int sg = 0; sg < 2; ++sg) {
            const float b = (sg == 0) ? cyf : -cyf;   // f32(sgn*cy)
            const float ax511 = a * 511.0f;
            const float by511 = b * 511.0f;
            float rmin, rmax;
            if (sg == 0) { rmin = 0.0f;  rmax = ax511 + by511; }
            else         { rmin = by511; rmax = ax511; }
            const float dr = rmax - rmin;
            const double K = 512.0 * ratio_f / (double)dr;
            const int pi = 2 * i + sg;
            P.ax[pi] = (float)(K * (double)a);
            P.ay[pi] = (float)(K * (double)b);
            P.c0[pi] = (float)(-K * (double)rmin);
        }
    }

    const int slices = in_sizes[0] / (WDIM * HDIM);  // B*C = 48
    const int blocks = slices * TILES_PER_SLICE;     // 3072
    stripe_poly_kernel<<<blocks, THREADS, 0, stream>>>(x, w, out, P);
}

// Round 4
// 113.980 us; speedup vs baseline: 1.2955x; 1.0292x over previous
//
#include <hip/hip_runtime.h>
#include <math.h>

// StripePolynomial2d: out[b,c,px,py] = sum_i lut_i(xs_i), where
//   xs_i = 0.5*x + Ax[i]*px + Ay[i]*py + C0[i]   (folded position map)
//   s = clamp(floor(xs),0,511); t = 2*(xs-s)-1; P = c0 + t*(c1 + t*c2)
// 1/8 normalization folded into staged coeffs; positions 0,1 merged
// (theta=0 => identical maps => sum their weights) -> 7 tables.
//
// Wave lane mapping covers a 16px x 16py patch: since K*(a+|b|) ~= 1.0 for
// every direction, per-gather segment spread ~16 for all positions ->
// conflict-free ds_read_b64 (verified: SQ_LDS_BANK_CONFLICT == 0).
//
// R4: 128x64 tile (4 k-iters/thread) + software prefetch of x[k+1] to break
// the per-k load convoy; staging amortized over 2x more pixels.

#define WDIM 512
#define HDIM 512
#define SEGS 512
#define NPOS 8
#define NTAB 7     // position 0+1 merged
#define NW   1025
#define CCH  3

#define THREADS 512
#define TILE_X 128
#define TILE_Y 64
#define KITER  4                              // px advances 32 per k
#define TILES_PER_SLICE ((WDIM / TILE_X) * (HDIM / TILE_Y))  // 32

struct Params {
    float ax[NPOS];
    float ay[NPOS];
    float c0[NPOS];
};

union HalfPack {
    unsigned int u;
    _Float16 h[2];
};

__global__ __launch_bounds__(THREADS, 8)
void stripe_poly_kernel(const float* __restrict__ x,
                        const float* __restrict__ w,
                        float* __restrict__ out,
                        Params P)
{
    // 7 tables x 512 segments x 8 B = 28 KB
    __shared__ uint2 lut[NTAB][SEGS];

    const int slice = blockIdx.x / TILES_PER_SLICE;   // b*3 + c
    const int tile  = blockIdx.x % TILES_PER_SLICE;
    const int ch    = slice % CCH;
    const int bx    = (tile >> 3) * TILE_X;   // px tile origin (4 x-tiles)
    const int by    = (tile & 7) * TILE_Y;    // py tile origin (8 y-tiles)

    // Stage coefficient LUT (1/8 folded in): 3584 entries / 512 thr = 7 ea.
    for (int idx = threadIdx.x; idx < NTAB * SEGS; idx += THREADS) {
        const int m = idx >> 9;            // merged table id
        const int s = idx & (SEGS - 1);
        float w0, w1, w2;
        if (m == 0) {
            const float* wa = w + (size_t)(0 * CCH + ch) * NW + 2 * s;
            const float* wb = w + (size_t)(1 * CCH + ch) * NW + 2 * s;
            w0 = wa[0] + wb[0]; w1 = wa[1] + wb[1]; w2 = wa[2] + wb[2];
        } else {
            const float* wp = w + (size_t)((m + 1) * CCH + ch) * NW + 2 * s;
            w0 = wp[0]; w1 = wp[1]; w2 = wp[2];
        }
        const float c0 = 0.125f * w1;
        const float c1 = 0.0625f * (w2 - w0);
        const float c2 = 0.125f * fmaf(0.5f, w0 + w2, -w1);
        HalfPack hp;
        hp.h[0] = (_Float16)c1;
        hp.h[1] = (_Float16)c2;
        lut[m][s] = make_uint2(__float_as_uint(c0), hp.u);
    }
    __syncthreads();

    // Lane -> patch mapping: each wave covers 16px x 16py per k.
    const int tid  = threadIdx.x;
    const int wv   = tid >> 6;
    const int lane = tid & 63;
    const int px0  = bx + (wv >> 2) * 16 + (lane >> 2);  // k adds 32
    const int py   = by + (wv & 3) * 16 + (lane & 3) * 4;
    const float yf = (float)py;

    const size_t slice_off = (size_t)slice * (WDIM * HDIM);
    const size_t pbase = slice_off + (size_t)px0 * HDIM + py;

    // Hoist y-dependent part of each position map (py fixed across k).
    float gy[NTAB];
    #pragma unroll
    for (int i = 0; i < NTAB; ++i) {
        const int pi = (i == 0) ? 0 : (i + 1);
        gy[i] = fmaf(P.ay[pi], yf, P.c0[pi]);
    }

    // Software-pipelined k loop: prefetch x for k+1 before computing k.
    float4 xin = *(const float4*)(x + pbase);
    #pragma unroll
    for (int k = 0; k < KITER; ++k) {
        const size_t pk = pbase + (size_t)(k * 32) * HDIM;
        float4 xnext;
        if (k + 1 < KITER)
            xnext = *(const float4*)(x + pk + (size_t)32 * HDIM);

        const float xf = (float)(px0 + k * 32);
        const float xv[4] = {xin.x, xin.y, xin.z, xin.w};
        float acc[4] = {0.f, 0.f, 0.f, 0.f};

        #pragma unroll
        for (int i = 0; i < NTAB; ++i) {
            const int pi = (i == 0) ? 0 : (i + 1);  // source position index
            const float ay = P.ay[pi];
            const float g  = fmaf(P.ax[pi], xf, gy[i]);
            float gj[4];
            gj[0] = g;
            gj[1] = g + ay;
            gj[2] = gj[1] + ay;
            gj[3] = gj[2] + ay;
            #pragma unroll
            for (int j = 0; j < 4; ++j) {
                const float xs = fmaf(0.5f, xv[j], gj[j]);
                float sf = floorf(xs);
                sf = fminf(fmaxf(sf, 0.0f), (float)(SEGS - 1));  // v_med3
                const int s = (int)sf;
                const float t = fmaf(2.0f, xs - sf, -1.0f);
                const uint2 v = lut[i][s];                 // ds_read_b64
                HalfPack hp; hp.u = v.y;
                const float u = fmaf(t, (float)hp.h[1], (float)hp.h[0]); // fma_mix
                acc[j] = fmaf(t, u, acc[j] + __uint_as_float(v.x));
            }
        }

        float4 o;
        o.x = acc[0]; o.y = acc[1]; o.z = acc[2]; o.w = acc[3];
        *(float4*)(out + pk) = o;
        xin = xnext;
    }
}

extern "C" void kernel_launch(void* const* d_in, const int* in_sizes, int n_in,
                              void* d_out, int out_size, void* d_ws, size_t ws_size,
                              hipStream_t stream)
{
    const float* x = (const float*)d_in[0];   // [16,3,512,512] f32
    const float* w = (const float*)d_in[1];   // [8,3,1025] f32
    float* out = (float*)d_out;

    // Host-side fold of make_positions() + position_encode + xs rescale.
    // r(x,y) = f32(cx)*x + f32(sgn*cy)*y ; extremes at grid corners (monotone).
    // xs = 0.5*xval + K*(r - rmin), K = 512*RATIO/dr  =>  Ax=K*a, Ay=K*b, C0=-K*rmin.
    Params P;
    const double ratio_f = (double)(float)(512.0 / 513.0);  // numpy casts RATIO to f32
    for (int i = 0; i < 4; ++i) {
        const double theta = (M_PI * 0.5) * ((double)i / 4.0);
        const float a   = (float)cos(theta);
        const float cyf = (float)sin(theta);
        for (int sg = 0; sg < 2; ++sg) {
            const float b = (sg == 0) ? cyf : -cyf;   // f32(sgn*cy)
            const float ax511 = a * 511.0f;
            const float by511 = b * 511.0f;
            float rmin, rmax;
            if (sg == 0) { rmin = 0.0f;  rmax = ax511 + by511; }
            else         { rmin = by511; rmax = ax511; }
            const float dr = rmax - rmin;
            const double K = 512.0 * ratio_f / (double)dr;
            const int pi = 2 * i + sg;
            P.ax[pi] = (float)(K * (double)a);
            P.ay[pi] = (float)(K * (double)b);
            P.c0[pi] = (float)(-K * (double)rmin);
        }
    }

    const int slices = in_sizes[0] / (WDIM * HDIM);  // B*C = 48
    const int blocks = slices * TILES_PER_SLICE;     // 1536
    stripe_poly_kernel<<<blocks, THREADS, 0, stream>>>(x, w, out, P);
}